// Round 14
// baseline (356.842 us; speedup 1.0000x reference)
//
#include <hip/hip_runtime.h>
#include <stdint.h>

typedef __bf16 bf16;
typedef __bf16 bf16x8 __attribute__((ext_vector_type(8)));
typedef float f32x4 __attribute__((ext_vector_type(4)));

// ---------------- async global->LDS (16B per lane) ----------------
static __device__ __forceinline__ void async16(const void* g, void* l) {
  __builtin_amdgcn_global_load_lds(
      (__attribute__((address_space(1))) void*)g,
      (__attribute__((address_space(3))) void*)l, 16, 0, 0);
}

// ---------------- merged prep ----------------
// blocks [0,512) Ttrig x4 | [512,2960) Atrig2 x4 | [2960,7056) cast x_dec x4 |
// [7056,11152) cast x_enc x4 | [11152,17296) weight transposes
// BtQ/BtK/BtV ALL use the h-in-bits-4:5 permuted row order n=(e&15)|(h<<4)|((e>>4)<<6)
// so the QKV epilogue gets h==ni: register-axis softmax (Q,K) and register-local
// transposed stores (K,V).
__global__ void __launch_bounds__(256) prep_all(
    const float* __restrict__ xdec, const float* __restrict__ xenc,
    bf16* __restrict__ Ttrig, bf16* __restrict__ Atrig2,
    bf16* __restrict__ xdec_b, bf16* __restrict__ xenc_b,
    const float* __restrict__ Wq, const float* __restrict__ Wk,
    const float* __restrict__ Wv, const float* __restrict__ Wo,
    const float* __restrict__ W1, const float* __restrict__ W2,
    bf16* __restrict__ BtQ, bf16* __restrict__ BtK, bf16* __restrict__ BtV,
    bf16* __restrict__ WoTh, bf16* __restrict__ W1T, bf16* __restrict__ W2T) {
  __shared__ bf16 tile[32][33];
  int id = blockIdx.x;
  if (id < 512) {                      // Ttrig[1024][512], 4 d/thread
    int idx = id * 256 + threadIdx.x;  // < 131072
    int d0 = (idx & 127) * 4, jp = idx >> 7;
    int jj = jp >> 1, p = jp & 1;
    bf16 o[4] __attribute__((aligned(8)));
#pragma unroll
    for (int i = 0; i < 4; ++i) {
      int tt = ((d0 + i) * jj) & 511;
      float ang = (float)tt * (6.283185307179586f / 512.0f);
      o[i] = (bf16)(p ? __sinf(ang) : __cosf(ang));
    }
    *(uint2*)(Ttrig + jp * 512 + d0) = *(const uint2*)o;
  } else if (id < 2960) {              // Atrig2[2][1152][1088], 4 k/thread
    int idx = (id - 512) * 256 + threadIdx.x;   // < 626688
    int k0 = (idx % 272) * 4;
    int rr = idx / 272;
    int r = rr % 1152, half = rr / 1152;
    bf16 o[4] __attribute__((aligned(8)));
#pragma unroll
    for (int i = 0; i < 4; ++i) {
      int k = k0 + i;
      float v = 0.0f;
      int tt = (r * k) & 2047;
      float ang = (float)tt * (6.283185307179586f / 2048.0f);
      if (half == 0) { if (r <= 1024 && k <= 1024) v = __cosf(ang); }
      else           { if (r <= 1023 && k >= 1 && k <= 1023) v = -__sinf(ang); }
      o[i] = (bf16)v;
    }
    *(uint2*)(Atrig2 + (long)rr * 1088 + k0) = *(const uint2*)o;
  } else if (id < 7056) {              // cast x_dec, 4 elems/thread
    int i = ((id - 2960) * 256 + threadIdx.x) * 4;
    float4 v = *(const float4*)(xdec + i);
    bf16 o[4] __attribute__((aligned(8))) =
        {(bf16)v.x, (bf16)v.y, (bf16)v.z, (bf16)v.w};
    *(uint2*)(xdec_b + i) = *(const uint2*)o;
  } else if (id < 11152) {             // cast x_enc, 4 elems/thread
    int i = ((id - 7056) * 256 + threadIdx.x) * 4;
    float4 v = *(const float4*)(xenc + i);
    bf16 o[4] __attribute__((aligned(8))) =
        {(bf16)v.x, (bf16)v.y, (bf16)v.z, (bf16)v.w};
    *(uint2*)(xenc_b + i) = *(const uint2*)o;
  } else {
    int id2 = id - 11152;
    int kind = id2 >> 10, t = id2 & 1023;
    const float* in; bf16* out; int R, C, rt, ct;
    bool iperm = false, hsel = false; int hh = 0;
    if (kind == 0)      { in = Wq; out = BtQ; R = 2048; C = 512; rt = t >> 4; ct = t & 15; iperm = true; }
    else if (kind == 1) { in = Wk; out = BtK; R = 2048; C = 512; rt = t >> 4; ct = t & 15; iperm = true; }
    else if (kind == 2) { in = Wv; out = BtV; R = 2048; C = 512; rt = t >> 4; ct = t & 15; iperm = true; }
    else if (kind == 3) {              // WoTh[h][n][e] = Wo[4e+h][n]
      int zz = t >> 8, tt = t & 255;
      in = Wo; out = WoTh + (long)zz * 262144;
      R = 512; C = 512; rt = tt >> 4; ct = tt & 15; hsel = true; hh = zz;
    }
    else if (kind == 4) { in = W1; out = W1T; R = 512; C = 2048; rt = t >> 6; ct = t & 63; }
    else                { in = W2; out = W2T; R = 2048; C = 512; rt = t >> 4; ct = t & 15; }
    int c0 = ct * 32, r0 = rt * 32;
    int tx = threadIdx.x & 31, ty = threadIdx.x >> 5;
#pragma unroll
    for (int i = 0; i < 32; i += 8) {
      int r = r0 + ty + i;
      int rr = hsel ? (4 * r + hh) : r;
      tile[ty + i][tx] = (bf16)in[(long)rr * C + (c0 + tx)];
    }
    __syncthreads();
#pragma unroll
    for (int i = 0; i < 32; i += 8) {
      int cc = c0 + ty + i, rr = r0 + tx;
      if (iperm) {  // Bt row from W row h*512+din; cc = e, rr>>9 = h, rr&511 = din
        int e = cc, h = rr >> 9;
        int n = (e & 15) | (h << 4) | ((e >> 4) << 6);
        out[((long)n << 9) + (rr & 511)] = tile[tx][ty + i];
      } else {
        out[(long)cc * R + rr] = tile[tx][ty + i];
      }
    }
  }
}

// Fold Yt [4][512][4096] -> Yf2 [8][512][1088], 4 elems/thread (4352 blocks).
__global__ void __launch_bounds__(256) fold_y(const bf16* __restrict__ Yt,
                                              bf16* __restrict__ Yf2) {
  int idx = blockIdx.x * 256 + threadIdx.x;   // 1114112 = 8*512*272
  int k0 = (idx % 272) * 4;
  int rr = idx / 272;
  int j = rr & 511, z = rr >> 9;
  int b = z & 3, half = z >> 2;
  const bf16* yin = Yt + (long)b * 2097152 + (long)j * 4096;
  bf16 o[4] __attribute__((aligned(8)));
  if (half == 0) {
    bf16 f[4] __attribute__((aligned(8)));
    *(uint2*)f = *(const uint2*)(yin + k0);      // Y[k0..k0+3]
#pragma unroll
    for (int i = 0; i < 4; ++i) {
      int k = k0 + i;
      float v;
      if (k == 0)            v = (float)f[0];
      else if (k == 1024)    v = (float)f[i];
      else if (k < 1024)     v = (float)f[i] + (float)yin[2048 - k];
      else                   v = 0.0f;
      o[i] = (bf16)v;
    }
  } else {
    bf16 f[4] __attribute__((aligned(8)));
    *(uint2*)f = *(const uint2*)(yin + 2048 + k0); // Ys[k0..k0+3]
#pragma unroll
    for (int i = 0; i < 4; ++i) {
      int k = k0 + i;
      float v = 0.0f;
      if (k >= 1 && k <= 1023) v = (float)f[i] - (float)yin[4096 - k];
      o[i] = (bf16)v;
    }
  }
  *(uint2*)(Yf2 + (long)z * 557056 + (long)j * 1088 + k0) = *(const uint2*)o;
}

// ---------------- LN1 with DFT recombination (pairwise vectorized) ----------------
__global__ void __launch_bounds__(256) ln1_kernel(
    const float* __restrict__ xdec, const bf16* __restrict__ CSb,
    const float* __restrict__ g, const float* __restrict__ be,
    bf16* __restrict__ outb) {
  const int row = blockIdx.x, t = threadIdx.x;
  const int b = row >> 11, s = row & 2047;
  const int sp = (s <= 1024) ? s : 2048 - s;
  const float sgn = (s <= 1024) ? 1.0f : -1.0f;
  const bf16* Crow = CSb + ((long)b * 1152 + sp) * 512;
  const bf16* Srow = CSb + ((long)(b + 4) * 1152 + sp) * 512;
  const long base = (long)row * 512;
  float2 xp = *(const float2*)(xdec + base + 2 * t);
  bf16 cp[2] __attribute__((aligned(4)));
  bf16 spv[2] __attribute__((aligned(4)));
  *(uint*)cp = *(const uint*)(Crow + 2 * t);
  *(uint*)spv = *(const uint*)(Srow + 2 * t);
  float v0 = xp.x + (float)cp[0] + sgn * (float)spv[0];
  float v1 = xp.y + (float)cp[1] + sgn * (float)spv[1];
  float sm = v0 + v1, q = v0 * v0 + v1 * v1;
#pragma unroll
  for (int off = 32; off > 0; off >>= 1) {
    sm += __shfl_down(sm, off);
    q += __shfl_down(q, off);
  }
  __shared__ float red[8];
  const int wv = t >> 6, ln = t & 63;
  if (ln == 0) { red[wv] = sm; red[wv + 4] = q; }
  __syncthreads();
  float S = red[0] + red[1] + red[2] + red[3];
  float Q = red[4] + red[5] + red[6] + red[7];
  float mu = S * (1.0f / 512.0f);
  float var = Q * (1.0f / 512.0f) - mu * mu;
  float rstd = rsqrtf(var + 1e-5f);
  float2 gp = *(const float2*)(g + 2 * t);
  float2 bp = *(const float2*)(be + 2 * t);
  bf16 op[2] __attribute__((aligned(4)));
  op[0] = (bf16)(gp.x * (v0 - mu) * rstd + bp.x);
  op[1] = (bf16)(gp.y * (v1 - mu) * rstd + bp.y);
  *(uint*)(outb + base + 2 * t) = *(const uint*)op;
}

// ---------------- LayerNorm over bf16 A + two f32 partials (split-K sum) ---------------
template <int WRITE_BF16, int WRITE_F32>
__global__ void __launch_bounds__(256) ln_sum2(
    const bf16* __restrict__ A, const float* __restrict__ P0,
    const float* __restrict__ P1,
    const float* __restrict__ g, const float* __restrict__ be,
    bf16* __restrict__ outb, float* __restrict__ outf) {
  const int row = blockIdx.x, t = threadIdx.x;
  const long base = (long)row * 512;
  bf16 ap[2] __attribute__((aligned(4)));
  *(uint*)ap = *(const uint*)(A + base + 2 * t);
  float2 p0 = *(const float2*)(P0 + base + 2 * t);
  float2 p1 = *(const float2*)(P1 + base + 2 * t);
  float v0 = (float)ap[0] + p0.x + p1.x;
  float v1 = (float)ap[1] + p0.y + p1.y;
  float s = v0 + v1, q = v0 * v0 + v1 * v1;
#pragma unroll
  for (int off = 32; off > 0; off >>= 1) {
    s += __shfl_down(s, off);
    q += __shfl_down(q, off);
  }
  __shared__ float red[8];
  const int wv = t >> 6, ln = t & 63;
  if (ln == 0) { red[wv] = s; red[wv + 4] = q; }
  __syncthreads();
  float S = red[0] + red[1] + red[2] + red[3];
  float Q = red[4] + red[5] + red[6] + red[7];
  float mu = S * (1.0f / 512.0f);
  float var = Q * (1.0f / 512.0f) - mu * mu;
  float rstd = rsqrtf(var + 1e-5f);
  float2 gp = *(const float2*)(g + 2 * t);
  float2 bp = *(const float2*)(be + 2 * t);
  float o0 = gp.x * (v0 - mu) * rstd + bp.x;
  float o1 = gp.y * (v1 - mu) * rstd + bp.y;
  if (WRITE_BF16) {
    bf16 op[2] __attribute__((aligned(4)));
    op[0] = (bf16)o0; op[1] = (bf16)o1;
    *(uint*)(outb + base + 2 * t) = *(const uint*)op;
  }
  if (WRITE_F32) {
    float2 of; of.x = o0; of.y = o1;
    *(float2*)(outf + base + 2 * t) = of;
  }
}

// ---------------- GEMM body: C = A[M,K] * Bt[N,K]^T (single-buffer m97 K-loop) ---------
template <int BN, int ADDR_MODE, int HAS_BIAS, int DO_SELU, int F32OUT, int SWIZ,
          int AHEAD>
static __device__ __forceinline__ void gemm_bt_body(
    int id, bf16* lA, bf16* lB,
    const bf16* __restrict__ A, const bf16* __restrict__ Bt,
    const float* __restrict__ bias, void* __restrict__ Cout,
    int N, int K, long sAz, long sBz, long sBiasz, long sCz,
    int gx, int gy, int gin) {
  int x, y, z;
  {
    if (SWIZ == 0) {
      x = id % gx; int t2 = id / gx; y = t2 % gy; z = t2 / gy;
    } else {
      int xcd = id & 7, r = id >> 3;
      int inner = r % gin, G = xcd + 8 * (r / gin);
      if (SWIZ == 1)      { y = G; x = inner % gx; z = inner / gx; }
      else if (SWIZ == 2) { z = G; x = inner % gx; y = inner / gx; }
      else                { x = G; y = inner % gy; z = inner / gy; }
    }
  }
  A  += (AHEAD == 1) ? sAz * (z & 3) : (AHEAD == 2) ? sAz * (z >> 2) : sAz * z;
  Bt += sBz * z;
  const int m0 = y * 128, n0 = x * BN;
  const int t = threadIdx.x;
  const int lane = t & 63, wave = t >> 6;
  const int srow = t >> 3;
  const int pch  = t & 7;
  const int lch  = pch ^ (srow & 7);   // XOR bank swizzle (global-side)
  const bf16* Ag = A  + (long)(m0 + srow) * K + lch * 8;
  const bf16* Bg = Bt + (long)(n0 + srow) * K + lch * 8;
  bf16* lAp = lA + srow * 64 + pch * 8;
  bf16* lBp = lB + srow * 64 + pch * 8;
  constexpr int MI = (BN == 128) ? 4 : 2;
  const int wm = (BN == 128) ? (wave >> 1) * 64 : wave * 32;
  const int wn = (BN == 128) ? (wave & 1) * 64 : 0;
  const int fr = lane & 15, fq = lane >> 4;

  f32x4 acc[MI][4] = {};

  for (int k0 = 0; k0 < K; k0 += 64) {
    __syncthreads();
#pragma unroll
    for (int i = 0; i < 4; ++i)
      async16(Ag + k0 + (long)(32 * i) * K, lAp + 32 * i * 64);
#pragma unroll
    for (int i = 0; i < BN / 32; ++i)
      async16(Bg + k0 + (long)(32 * i) * K, lBp + 32 * i * 64);
    __syncthreads();
#pragma unroll
    for (int kk = 0; kk < 2; ++kk) {
      bf16x8 av[MI], bfrag[4];
#pragma unroll
      for (int mi = 0; mi < MI; ++mi) {
        int r = wm + mi * 16 + fr;
        int c = (kk * 4 + fq) ^ (r & 7);
        av[mi] = *(const bf16x8*)&lA[r * 64 + c * 8];
      }
#pragma unroll
      for (int ni = 0; ni < 4; ++ni) {
        int r = wn + ni * 16 + fr;
        int c = (kk * 4 + fq) ^ (r & 7);
        bfrag[ni] = *(const bf16x8*)&lB[r * 64 + c * 8];
      }
#pragma unroll
      for (int mi = 0; mi < MI; ++mi)
#pragma unroll
        for (int ni = 0; ni < 4; ++ni)
          acc[mi][ni] = __builtin_amdgcn_mfma_f32_16x16x32_bf16(
              av[mi], bfrag[ni], acc[mi][ni], 0, 0, 0);
    }
  }

  // epilogue: C/D layout col = lane&15, row = (lane>>4)*4 + reg
#pragma unroll
  for (int mi = 0; mi < MI; ++mi) {
#pragma unroll
    for (int ni = 0; ni < 4; ++ni) {
      const int col = n0 + wn + ni * 16 + fr;
      float bias_v = 0.0f;
      if (HAS_BIAS == 1) bias_v = bias[sBiasz * z + col];
      if (ADDR_MODE == 9) {                  // z=b*4+h -> Bt_b[row][(col&15)|(h<<4)|((col>>4)<<6)]
        const int b = z >> 2, h = z & 3;
        const int kidx = (col & 15) | (h << 4) | ((col >> 4) << 6);
#pragma unroll
        for (int r = 0; r < 4; ++r) {
          const int row = m0 + wm + mi * 16 + fq * 4 + r;
          ((bf16*)Cout)[((long)(b * 512 + row)) * 2048 + kidx] =
              (bf16)(acc[mi][ni][r] + bias_v);
        }
      } else {
#pragma unroll
        for (int r = 0; r < 4; ++r) {
          const int row = m0 + wm + mi * 16 + fq * 4 + r;
          float v = acc[mi][ni][r] + bias_v;
          if (DO_SELU) v = v > 0.0f ? 1.0507009873554805f * v
                                    : 1.7580993408473766f * (__expf(v) - 1.0f);
          long addr = sCz * z + (long)row * N + col;
          if (F32OUT) ((float*)Cout)[addr] = v;
          else        ((bf16*)Cout)[addr] = (bf16)v;
        }
      }
    }
  }
}

// standalone wrapper
template <int BN, int ADDR_MODE, int HAS_BIAS, int DO_SELU, int F32OUT, int SWIZ,
          int AHEAD = 0>
__global__ void __launch_bounds__(256, 2) gemm_bt(
    const bf16* __restrict__ A, const bf16* __restrict__ Bt,
    const float* __restrict__ bias, void* __restrict__ Cout,
    int N, int K, long sAz, long sBz, long sBiasz, long sCz,
    int gx, int gy, int gin) {
  __shared__ __align__(16) bf16 lA[128 * 64];
  __shared__ __align__(16) bf16 lB[BN * 64];
  gemm_bt_body<BN, ADDR_MODE, HAS_BIAS, DO_SELU, F32OUT, SWIZ, AHEAD>(
      blockIdx.x, lA, lB, A, Bt, bias, Cout, N, K, sAz, sBz, sBiasz, sCz, gx, gy, gin);
}

// ---------------- split-K dual-N GEMM: 128x128 output, K halved, f32 partials ----------
// Shapes here: K=2048, N=512, A row-stride 2048. Two 64-wide N-tiles share the A tile:
// per k-step 8 global_load_lds -> 32 MFMA (2x the BN=64 density). 512 blocks, 32KiB LDS.
// Z4=1 (attn): z in [0,4) batches, y in [0,16). Z4=0 (W2): y in [0,64).
// Partial P[ks][row][col] f32; bias added once (ks==0); summed by ln_sum2.
template <int Z4>
__global__ void __launch_bounds__(256, 2) gemm_sk2(
    const bf16* __restrict__ A, const bf16* __restrict__ Bt,
    const float* __restrict__ bias,
    float* __restrict__ P0, float* __restrict__ P1,
    long sAz, long sBz) {
  __shared__ __align__(16) bf16 lA[128 * 64];
  __shared__ __align__(16) bf16 lB[2][64 * 64];
  const int id = blockIdx.x;            // [0,512)
  const int xcd = id & 7, r = id >> 3;  // r in [0,64)
  const int xp = r & 3;
  int y, z, ks;
  if (Z4) { z = xcd >> 1; ks = xcd & 1; y = r >> 2; }
  else    { z = 0; ks = xcd & 1; y = (xcd >> 1) * 16 + (r >> 2); }
  const int K = 2048, KH = 1024;
  A  += (long)z * sAz + (long)ks * KH;
  Bt += (long)z * sBz + (long)ks * KH;
  const int m0 = y * 128, n0 = xp * 128;
  const int t = threadIdx.x;
  const int lane = t & 63, wave = t >> 6;
  const int srow = t >> 3, pch = t & 7, lch = pch ^ (srow & 7);
  const bf16* Ag  = A  + (long)(m0 + srow) * K + lch * 8;
  const bf16* B0g = Bt + (long)(n0 + srow) * K + lch * 8;
  const bf16* B1g = Bt + (long)(n0 + 64 + srow) * K + lch * 8;
  bf16* lAp  = lA + srow * 64 + pch * 8;
  bf16* lB0p = lB[0] + srow * 64 + pch * 8;
  bf16* lB1p = lB[1] + srow * 64 + pch * 8;
  const int wm = wave * 32;             // 4 waves x 32 rows
  const int fr = lane & 15, fq = lane >> 4;

  f32x4 acc[2][2][4] = {};              // [set][mi][ni]
  for (int k0 = 0; k0 < KH; k0 += 64) {
    __syncthreads();
#pragma unroll
    for (int i = 0; i < 4; ++i)
      async16(Ag + k0 + (long)(32 * i) * K, lAp + 32 * i * 64);
#pragma unroll
    for (int i = 0; i < 2; ++i) {
      async16(B0g + k0 + (long)(32 * i) * K, lB0p + 32 * i * 64);
      async16(B1g + k0 + (long)(32 * i) * K, lB1p + 32 * i * 64);
    }
    __syncthreads();
#pragma unroll
    for (int kk = 0; kk < 2; ++kk) {
      bf16x8 av[2];
#pragma unroll
      for (int mi = 0; mi < 2; ++mi) {
        int rr = wm + mi * 16 + fr;
        int c = (kk * 4 + fq) ^ (rr & 7);
        av[mi] = *(const bf16x8*)&lA[rr * 64 + c * 8];
      }
#pragma unroll
      for (int s = 0; s < 2; ++s) {
        bf16x8 bfrag[4];
#pragma unroll
        for (int ni = 0; ni < 4; ++ni) {
          int rr = ni * 16 + fr;
          int c = (kk * 4 + fq) ^ (rr & 7);
          bfrag[ni] = *(const bf16x8*)&lB[s][rr * 64 + c * 8];
        }
#pragma unroll
        for (int mi = 0; mi < 2; ++mi)
#pragma unroll
          for (int ni = 0; ni < 4; ++ni)
            acc[s][mi][ni] = __builtin_amdgcn_mfma_f32_16x16x32_bf16(
                av[mi], bfrag[ni], acc[s][mi][ni], 0, 0, 0);
      }
    }
  }

  float* P = ks ? P1 : P0;
#pragma unroll
  for (int s = 0; s < 2; ++s) {
#pragma unroll
    for (int mi = 0; mi < 2; ++mi) {
#pragma unroll
      for (int ni = 0; ni < 4; ++ni) {
        const int col = n0 + s * 64 + ni * 16 + fr;
        const float bias_v = (ks == 0) ? bias[col] : 0.0f;
#pragma unroll
        for (int r2 = 0; r2 < 4; ++r2) {
          const int row = m0 + wm + mi * 16 + fq * 4 + r2;
          const long addr = ((long)(Z4 ? z * 2048 + row : row)) * 512 + col;
          P[addr] = acc[s][mi][ni][r2] + bias_v;
        }
      }
    }
  }
}

// ---------------- Q projection GEMM body (id in [0,1024)) ------------------------------
// BtQ permuted row order -> h == ni: register-axis head-softmax, writes qs2 (kidx).
static __device__ __forceinline__ void qkv_body(
    int id, bf16* lA, bf16* lB,
    const bf16* __restrict__ Aq,
    const bf16* __restrict__ BQ,
    const float* __restrict__ bq,
    bf16* __restrict__ qs2) {
  const int sid = id & 1023;
  const int xcd = sid & 7, r = sid >> 3;
  const int x = r & 15, y = xcd + 8 * (r >> 4);
  const bf16 *A = Aq, *Bt = BQ; bf16* out = qs2; const float* bias = bq;
  const int K = 512;
  const int m0 = y * 128, n0 = x * 128;
  const int t = threadIdx.x;
  const int lane = t & 63, wave = t >> 6;
  const int srow = t >> 3, pch = t & 7, lch = pch ^ (srow & 7);
  const bf16* Ag = A  + (long)(m0 + srow) * K + lch * 8;
  const bf16* Bg = Bt + (long)(n0 + srow) * K + lch * 8;
  bf16* lAp = lA + srow * 64 + pch * 8;
  bf16* lBp = lB + srow * 64 + pch * 8;
  const int wm = (wave >> 1) * 64, wn = (wave & 1) * 64;
  const int fr = lane & 15, fq = lane >> 4;

  f32x4 acc[4][4] = {};
  for (int k0 = 0; k0 < K; k0 += 64) {
    __syncthreads();
#pragma unroll
    for (int i = 0; i < 4; ++i) {
      async16(Ag + k0 + (long)(32 * i) * K, lAp + 32 * i * 64);
      async16(Bg + k0 + (long)(32 * i) * K, lBp + 32 * i * 64);
    }
    __syncthreads();
#pragma unroll
    for (int kk = 0; kk < 2; ++kk) {
      bf16x8 av[4], bfrag[4];
#pragma unroll
      for (int mi = 0; mi < 4; ++mi) {
        int rr = wm + mi * 16 + fr;
        int c = (kk * 4 + fq) ^ (rr & 7);
        av[mi] = *(const bf16x8*)&lA[rr * 64 + c * 8];
      }
#pragma unroll
      for (int ni = 0; ni < 4; ++ni) {
        int rr = wn + ni * 16 + fr;
        int c = (kk * 4 + fq) ^ (rr & 7);
        bfrag[ni] = *(const bf16x8*)&lB[rr * 64 + c * 8];
      }
#pragma unroll
      for (int mi = 0; mi < 4; ++mi)
#pragma unroll
        for (int ni = 0; ni < 4; ++ni)
          acc[mi][ni] = __builtin_amdgcn_mfma_f32_16x16x32_bf16(
              av[mi], bfrag[ni], acc[mi][ni], 0, 0, 0);
    }
  }

  // h == ni; e = fr + 16*((n0+wn)>>6). Softmax across ni in registers.
  const int ebase = fr + 16 * ((n0 + wn) >> 6);
  const float b0 = bias[ebase], b1 = bias[512 + ebase],
              b2 = bias[1024 + ebase], b3 = bias[1536 + ebase];
#pragma unroll
  for (int mi = 0; mi < 4; ++mi) {
#pragma unroll
    for (int r = 0; r < 4; ++r) {
      const int row = m0 + wm + mi * 16 + fq * 4 + r;
      float v0 = acc[mi][0][r] + b0;
      float v1 = acc[mi][1][r] + b1;
      float v2 = acc[mi][2][r] + b2;
      float v3 = acc[mi][3][r] + b3;
      float m = fmaxf(fmaxf(v0, v1), fmaxf(v2, v3));
      float p0 = __expf(v0 - m), p1 = __expf(v1 - m),
            p2 = __expf(v2 - m), p3 = __expf(v3 - m);
      float rs = 1.0f / (p0 + p1 + p2 + p3);
      const long ob = (long)row * 2048 + n0 + wn + fr;
      out[ob]      = (bf16)(p0 * rs);
      out[ob + 16] = (bf16)(p1 * rs);
      out[ob + 32] = (bf16)(p2 * rs);
      out[ob + 48] = (bf16)(p3 * rs);
    }
  }
}

// ---------------- merged K+V projection body (id in [0,1024)) --------------------------
static __device__ __forceinline__ void kv2_body(
    int sid, bf16* smem,
    const bf16* __restrict__ Aenc, const bf16* __restrict__ BK,
    const bf16* __restrict__ BV,
    const float* __restrict__ bk, const float* __restrict__ bv,
    bf16* __restrict__ ksT, bf16* __restrict__ vsT) {
  const int xcd = sid & 7, r = sid >> 3;
  const int x = r & 15, y = xcd + 8 * (r >> 4);
  const int K = 512;
  const int m0 = y * 128, n0 = x * 128;
  const int t = threadIdx.x;
  const int lane = t & 63, wave = t >> 6;
  const int srow = t >> 3, pch = t & 7, lch = pch ^ (srow & 7);
  bf16* lA  = smem;           // [0,8192) elems
  bf16* lBK = smem + 8192;    // [8192,16384)
  bf16* lBV = smem + 16384;   // [16384,24576)
  const bf16* Ag  = Aenc + (long)(m0 + srow) * K + lch * 8;
  const bf16* BKg = BK   + (long)(n0 + srow) * K + lch * 8;
  const bf16* BVg = BV   + (long)(n0 + srow) * K + lch * 8;
  bf16* lAp  = lA  + srow * 64 + pch * 8;
  bf16* lBKp = lBK + srow * 64 + pch * 8;
  bf16* lBVp = lBV + srow * 64 + pch * 8;
  const int wm = (wave >> 1) * 64, wn = (wave & 1) * 64;
  const int fr = lane & 15, fq = lane >> 4;

  f32x4 accK[4][4] = {}, accV[4][4] = {};
  for (int k0 = 0; k0 < K; k0 += 64) {
    __syncthreads();
#pragma unroll
    for (int i = 0; i < 4; ++i) {
      async16(Ag  + k0 + (long)(32 * i) * K, lAp  + 32 * i * 64);
      async16(BKg + k0 + (long)(32 * i) * K, lBKp + 32 * i * 64);
      async16(BVg + k0 + (long)(32 * i) * K, lBVp + 32 * i * 64);
    }
    __syncthreads();
#pragma unroll
    for (int kk = 0; kk < 2; ++kk) {
      bf16x8 av[4], bkf[4], bvf[4];
#pragma unroll
      for (int mi = 0; mi < 4; ++mi) {
        int rr = wm + mi * 16 + fr;
        int c = (kk * 4 + fq) ^ (rr & 7);
        av[mi] = *(const bf16x8*)&lA[rr * 64 + c * 8];
      }
#pragma unroll
      for (int ni = 0; ni < 4; ++ni) {
        int rr = wn + ni * 16 + fr;
        int c = (kk * 4 + fq) ^ (rr & 7);
        bkf[ni] = *(const bf16x8*)&lBK[rr * 64 + c * 8];
        bvf[ni] = *(const bf16x8*)&lBV[rr * 64 + c * 8];
      }
#pragma unroll
      for (int mi = 0; mi < 4; ++mi)
#pragma unroll
        for (int ni = 0; ni < 4; ++ni) {
          accK[mi][ni] = __builtin_amdgcn_mfma_f32_16x16x32_bf16(
              av[mi], bkf[ni], accK[mi][ni], 0, 0, 0);
          accV[mi][ni] = __builtin_amdgcn_mfma_f32_16x16x32_bf16(
              av[mi], bvf[ni], accV[mi][ni], 0, 0, 0);
        }
    }
  }

  // h == ni; feature index e = fr + 16*((n0+wn)>>6).
  const int ebase = fr + 16 * ((n0 + wn) >> 6);
  const float kb0 = bk[ebase], kb1 = bk[512 + ebase],
              kb2 = bk[1024 + ebase], kb3 = bk[1536 + ebase];
  const float vb0 = bv[ebase], vb1 = bv[512 + ebase],
              vb2 = bv[1024 + ebase], vb3 = bv[1536 + ebase];
  bf16* lT = smem;                       // 32 KiB contiguous (lA+lBK)
  const int bb = m0 >> 11;
  const int s_tile = m0 & 2047;
  const int e_loc = fr + 16 * (wn >> 6); // [0,32)
  const int c = lane & 15, rg = lane >> 4;

  // ---- K (softmax) ----
  __syncthreads();                       // all LDS reads of lA/lBK/lBV done
#pragma unroll
  for (int mi = 0; mi < 4; ++mi) {
    const int s0 = wm + mi * 16 + fq * 4;
    bf16 tmp[4][4] __attribute__((aligned(8)));   // [h][r]
#pragma unroll
    for (int r2 = 0; r2 < 4; ++r2) {
      float v0 = accK[mi][0][r2] + kb0;
      float v1 = accK[mi][1][r2] + kb1;
      float v2 = accK[mi][2][r2] + kb2;
      float v3 = accK[mi][3][r2] + kb3;
      float m = fmaxf(fmaxf(v0, v1), fmaxf(v2, v3));
      float p0 = __expf(v0 - m), p1 = __expf(v1 - m),
            p2 = __expf(v2 - m), p3 = __expf(v3 - m);
      float rs = 1.0f / (p0 + p1 + p2 + p3);
      tmp[0][r2] = (bf16)(p0 * rs); tmp[1][r2] = (bf16)(p1 * rs);
      tmp[2][r2] = (bf16)(p2 * rs); tmp[3][r2] = (bf16)(p3 * rs);
    }
#pragma unroll
    for (int ni = 0; ni < 4; ++ni) {
      const int row = ni * 32 + e_loc;
      const int el = row * 128 + ((((s0 >> 3) ^ (row & 15)) << 3) | (s0 & 7));
      *(uint2*)&lT[el] = *(const uint2*)tmp[ni];
    }
  }
  __syncthreads();
#pragma unroll
  for (int i = 0; i < 8; ++i) {
    const int row = wave * 32 + rg + i * 4;
    const int el = row * 128 + ((c ^ (row & 15)) << 3);
    uint4 v = *(const uint4*)&lT[el];
    const int h = row >> 5, e = (row & 31) + 32 * x;
    *(uint4*)(ksT + ((long)((bb * 4 + h) * 512 + e)) * 2048 + s_tile + c * 8) = v;
  }

  // ---- V (no softmax) ----
  __syncthreads();                       // lT reads complete
#pragma unroll
  for (int mi = 0; mi < 4; ++mi) {
    const int s0 = wm + mi * 16 + fq * 4;
    bf16 tmp[4][4] __attribute__((aligned(8)));
#pragma unroll
    for (int r2 = 0; r2 < 4; ++r2) {
      tmp[0][r2] = (bf16)(accV[mi][0][r2] + vb0);
      tmp[1][r2] = (bf16)(accV[mi][1][r2] + vb1);
      tmp[2][r2] = (bf16)(accV[mi][2][r2] + vb2);
      tmp[3][r2] = (bf16)(accV[mi][3][r2] + vb3);
    }
#pragma unroll
    for (int ni = 0; ni < 4; ++ni) {
      const int row = ni * 32 + e_loc;
      const int el = row * 128 + ((((s0 >> 3) ^ (row & 15)) << 3) | (s0 & 7));
      *(uint2*)&lT[el] = *(const uint2*)tmp[ni];
    }
  }
  __syncthreads();
#pragma unroll
  for (int i = 0; i < 8; ++i) {
    const int row = wave * 32 + rg + i * 4;
    const int el = row * 128 + ((c ^ (row & 15)) << 3);
    uint4 v = *(const uint4*)&lT[el];
    const int h = row >> 5, e = (row & 31) + 32 * x;
    *(uint4*)(vsT + ((long)((bb * 4 + h) * 512 + e)) * 2048 + s_tile + c * 8) = v;
  }
}

// ---------------- fused launches ----------------
// [0,1024): merged K+V projection | [1024,1536): Yt DFT GEMM
__global__ void __launch_bounds__(256, 2) fused_kv_yt(
    const bf16* __restrict__ Aenc, const bf16* __restrict__ BK,
    const bf16* __restrict__ BV,
    const float* __restrict__ bk, const float* __restrict__ bv,
    bf16* __restrict__ ksT, bf16* __restrict__ vsT,
    const bf16* __restrict__ Ttrig, const bf16* __restrict__ xdec_b,
    bf16* __restrict__ Yt) {
  __shared__ __align__(16) bf16 smem[24576];   // 48 KiB
  int id = blockIdx.x;
  if (id < 1024)
    kv2_body(id, smem, Aenc, BK, BV, bk, bv, ksT, vsT);
  else
    gemm_bt_body<128, 0, 0, 0, 0, 3, 0>(id - 1024, smem, smem + 8192,
        Ttrig, xdec_b, nullptr, Yt, 2048, 512, 0L, 1048576L, 0L, 2097152L, 16, 8, 32);
}

// [0,512): gc GEMM | [512,1088): CS GEMM
__global__ void __launch_bounds__(256, 2) fused_gc_cs(
    const bf16* __restrict__ ksT, const bf16* __restrict__ vsT,
    bf16* __restrict__ gc,
    const bf16* __restrict__ Atrig2, const bf16* __restrict__ Yf2,
    bf16* __restrict__ CSb) {
  __shared__ __align__(16) bf16 smem[12288];   // 24 KiB
  int id = blockIdx.x;
  if (id < 512)
    gemm_bt_body<64, 0, 0, 0, 0, 2, 0>(id, smem, smem + 8192,
        ksT, vsT, nullptr, gc, 512, 2048, 1048576L, 1048576L, 0L, 262144L, 8, 4, 32);
  else
    gemm_bt_body<64, 0, 0, 0, 0, 2, 2>(id - 512, smem, smem + 8192,
        Atrig2, Yf2, nullptr, CSb, 512, 1088, 1253376L, 557056L, 0L, 589824L, 8, 9, 72);
}

// [0,1024): Q projection + head-softmax | [1024,1536): gwT GEMM (kidx layout)
__global__ void __launch_bounds__(256, 2) fused_q_gw(
    const bf16* __restrict__ Aq, const bf16* __restrict__ BQ,
    const float* __restrict__ bq, bf16* __restrict__ qs2,
    const bf16* __restrict__ WoTh, const bf16* __restrict__ gc,
    bf16* __restrict__ gwT) {
  __shared__ __align__(16) bf16 smem[16384];   // 32 KiB
  int id = blockIdx.x;
  if (id < 1024)
    qkv_body(id, smem, smem + 8192, Aq, BQ, bq, qs2);
  else
    gemm_bt_body<64, 9, 0, 0, 0, 2, 1>(id - 1024, smem, smem + 8192,
        WoTh, gc, nullptr, gwT, 512, 512, 262144L, 262144L, 0L, 0L, 8, 4, 32);
}

// ---------------- launcher ----------------
extern "C" void kernel_launch(void* const* d_in, const int* in_sizes, int n_in,
                              void* d_out, int out_size, void* d_ws, size_t ws_size,
                              hipStream_t stream) {
  (void)in_sizes; (void)n_in; (void)out_size; (void)ws_size;
  const float* x_enc = (const float*)d_in[0];
  const float* x_dec = (const float*)d_in[1];
  const float* Wq = (const float*)d_in[2];
  const float* bq = (const float*)d_in[3];
  const float* Wk = (const float*)d_in[4];
  const float* bk = (const float*)d_in[5];
  const float* Wv = (const float*)d_in[6];
  const float* bv = (const float*)d_in[7];
  const float* Wo = (const float*)d_in[8];
  const float* bo = (const float*)d_in[9];
  const float* g1 = (const float*)d_in[10];
  const float* be1 = (const float*)d_in[11];
  const float* g2 = (const float*)d_in[12];
  const float* be2 = (const float*)d_in[13];
  const float* W1 = (const float*)d_in[14];
  const float* b1 = (const float*)d_in[15];
  const float* W2 = (const float*)d_in[16];
  const float* b2 = (const float*)d_in[17];
  const float* g3 = (const float*)d_in[18];
  const float* be3 = (const float*)d_in[19];

  char* ws = (char*)d_ws;
  const size_t MB = 1u << 20;
  // time-disjoint aliasing, peak 255 MiB. Launch order:
  // L1 prep | L2 kv+yt | L3 fold | L4 gc+cs | L5 ln1 | L6 q+gw | L7 attn(sk2)
  // L8 ln2(sum2) | L9 w1 | L10 w2(sk2) | L11 ln3(sum2)
  bf16*  BtQ    = (bf16*) (ws + 0);        // [0,2)   W:L1 R:L6
  bf16*  midb   = (bf16*) (ws + 0);        // [0,32)  W:L9 R:L10
  bf16*  ksT    = (bf16*) (ws + 32 * MB);  // [32,64) W:L2 R:L4
  float* aP0    = (float*)(ws + 32 * MB);  // [32,48) W:L7 R:L8 (ksT dead after L4)
  float* aP1    = (float*)(ws + 48 * MB);  // [48,64) W:L7 R:L8
  bf16*  vsT    = (bf16*) (ws + 64 * MB);  // [64,96) W:L2 R:L4
  bf16*  Atrig2 = (bf16*) (ws + 96 * MB);  // [96,101) W:L1 R:L4
  bf16*  Ttrig  = (bf16*) (ws + 101 * MB); // [101,102) W:L1 R:L2
  bf16*  CSb    = (bf16*) (ws + 102 * MB); // [102,112) W:L4 R:L5
  bf16*  qs2    = (bf16*) (ws + 96 * MB);  // [96,128) W:L6 R:L7
  bf16*  xenc_b = (bf16*) (ws + 128 * MB); // [128,136) W:L1 R:L2
  float* wP0    = (float*)(ws + 128 * MB); // [128,144) W:L10 R:L11 (dead regions)
  float* wP1    = (float*)(ws + 144 * MB); // [144,160) W:L10 R:L11
  bf16*  BtK    = (bf16*) (ws + 136 * MB); // [136,138) W:L1 R:L2
  bf16*  BtV    = (bf16*) (ws + 138 * MB); // [138,140) W:L1 R:L2
  bf16*  xd_b   = (bf16*) (ws + 192 * MB); // [192,200) W:L5 R:L6,L8
  bf16*  x2_b   = (bf16*) (ws + 200 * MB); // [200,208) W:L8 R:L9,L11
  bf16*  gwT    = (bf16*) (ws + 208 * MB); // [208,216) W:L6 R:L7
  bf16*  Yt     = (bf16*) (ws + 216 * MB); // [216,232) W:L2 R:L3
  bf16*  gc     = (bf16*) (ws + 216 * MB); // [216,224) W:L4 R:L6 (Yt dead after L3)
  bf16*  Yf2    = (bf16*) (ws + 232 * MB); // [232,241) W:L3 R:L4
  bf16*  WoTh   = (bf16*) (ws + 241 * MB); // [241,243) W:L1 R:L6
  bf16*  W1T    = (bf16*) (ws + 243 * MB); // W:L1 R:L9
  bf16*  W2T    = (bf16*) (ws + 245 * MB); // W:L1 R:L10
  bf16*  xdec_b = (bf16*) (ws + 247 * MB); // [247,255) W:L1 R:L2

  // --- L1: prep (trig + casts x4-vectorized) ---
  prep_all<<<17296, 256, 0, stream>>>(x_dec, x_enc, Ttrig, Atrig2, xdec_b, xenc_b,
                                      Wq, Wk, Wv, Wo, W1, W2,
                                      BtQ, BtK, BtV, WoTh, W1T, W2T);

  // --- L2: merged K+V projection (A-tile shared)  ∥  Yt DFT GEMM ---
  fused_kv_yt<<<1536, 256, 0, stream>>>(xenc_b, BtK, BtV, bk, bv, ksT, vsT,
                                        Ttrig, xdec_b, Yt);

  // --- L3: fold (4 elems/thread) ---
  fold_y<<<4352, 256, 0, stream>>>(Yt, Yf2);

  // --- L4: gc GEMM  ∥  CS GEMM ---
  fused_gc_cs<<<1088, 256, 0, stream>>>(ksT, vsT, gc, Atrig2, Yf2, CSb);

  // --- L5: LN1 ---
  ln1_kernel<<<8192, 256, 0, stream>>>(x_dec, CSb, g1, be1, xd_b);

  // --- L6: Q projection+softmax  ∥  gwT ---
  fused_q_gw<<<1536, 256, 0, stream>>>(xd_b, BtQ, bq, qs2, WoTh, gc, gwT);

  // --- L7: attn split-K dual-N: partials P0/P1 (f32), bias once ---
  gemm_sk2<1><<<512, 256, 0, stream>>>(qs2, gwT, bo, aP0, aP1,
                                       4194304L, 1048576L);
  // --- L8: LN2 over xd + P0 + P1 ---
  ln_sum2<1, 0><<<8192, 256, 0, stream>>>(xd_b, aP0, aP1, g2, be2, x2_b, nullptr);

  // --- L9: FFN W1 + SELU ---
  gemm_bt<128, 0, 1, 1, 0, 1><<<1024, 256, 0, stream>>>(
      x2_b, W1T, b1, midb, 2048, 512, 0L, 0L, 0L, 0L, 16, 64, 16);
  // --- L10: FFN W2 split-K dual-N: partials (f32) ---
  gemm_sk2<0><<<512, 256, 0, stream>>>(midb, W2T, b2, wP0, wP1, 0L, 0L);
  // --- L11: LN3 over x2 + P0 + P1 -> output (f32) ---
  ln_sum2<0, 1><<<8192, 256, 0, stream>>>(x2_b, wP0, wP1, g3, be3, nullptr,
                                          (float*)d_out);
}

// Round 15
// 336.312 us; speedup vs baseline: 1.0610x; 1.0610x over previous
//
#include <hip/hip_runtime.h>
#include <stdint.h>

typedef __bf16 bf16;
typedef __bf16 bf16x8 __attribute__((ext_vector_type(8)));
typedef float f32x4 __attribute__((ext_vector_type(4)));

// ---------------- async global->LDS (16B per lane) ----------------
static __device__ __forceinline__ void async16(const void* g, void* l) {
  __builtin_amdgcn_global_load_lds(
      (__attribute__((address_space(1))) void*)g,
      (__attribute__((address_space(3))) void*)l, 16, 0, 0);
}

// ---------------- merged prep ----------------
// blocks [0,512) Ttrig x4 | [512,2960) Atrig2 x4 | [2960,7056) cast x_dec x4 |
// [7056,11152) cast x_enc x4 | [11152,17296) weight transposes
// BtQ/BtK/BtV ALL use the h-in-bits-4:5 permuted row order n=(e&15)|(h<<4)|((e>>4)<<6)
// so the QKV epilogue gets h==ni: register-axis softmax (Q,K) and register-local
// transposed stores (K,V).
__global__ void __launch_bounds__(256) prep_all(
    const float* __restrict__ xdec, const float* __restrict__ xenc,
    bf16* __restrict__ Ttrig, bf16* __restrict__ Atrig2,
    bf16* __restrict__ xdec_b, bf16* __restrict__ xenc_b,
    const float* __restrict__ Wq, const float* __restrict__ Wk,
    const float* __restrict__ Wv, const float* __restrict__ Wo,
    const float* __restrict__ W1, const float* __restrict__ W2,
    bf16* __restrict__ BtQ, bf16* __restrict__ BtK, bf16* __restrict__ BtV,
    bf16* __restrict__ WoTh, bf16* __restrict__ W1T, bf16* __restrict__ W2T) {
  __shared__ bf16 tile[32][33];
  int id = blockIdx.x;
  if (id < 512) {                      // Ttrig[1024][512], 4 d/thread
    int idx = id * 256 + threadIdx.x;  // < 131072
    int d0 = (idx & 127) * 4, jp = idx >> 7;
    int jj = jp >> 1, p = jp & 1;
    bf16 o[4] __attribute__((aligned(8)));
#pragma unroll
    for (int i = 0; i < 4; ++i) {
      int tt = ((d0 + i) * jj) & 511;
      float ang = (float)tt * (6.283185307179586f / 512.0f);
      o[i] = (bf16)(p ? __sinf(ang) : __cosf(ang));
    }
    *(uint2*)(Ttrig + jp * 512 + d0) = *(const uint2*)o;
  } else if (id < 2960) {              // Atrig2[2][1152][1088], 4 k/thread
    int idx = (id - 512) * 256 + threadIdx.x;   // < 626688
    int k0 = (idx % 272) * 4;
    int rr = idx / 272;
    int r = rr % 1152, half = rr / 1152;
    bf16 o[4] __attribute__((aligned(8)));
#pragma unroll
    for (int i = 0; i < 4; ++i) {
      int k = k0 + i;
      float v = 0.0f;
      int tt = (r * k) & 2047;
      float ang = (float)tt * (6.283185307179586f / 2048.0f);
      if (half == 0) { if (r <= 1024 && k <= 1024) v = __cosf(ang); }
      else           { if (r <= 1023 && k >= 1 && k <= 1023) v = -__sinf(ang); }
      o[i] = (bf16)v;
    }
    *(uint2*)(Atrig2 + (long)rr * 1088 + k0) = *(const uint2*)o;
  } else if (id < 7056) {              // cast x_dec, 4 elems/thread
    int i = ((id - 2960) * 256 + threadIdx.x) * 4;
    float4 v = *(const float4*)(xdec + i);
    bf16 o[4] __attribute__((aligned(8))) =
        {(bf16)v.x, (bf16)v.y, (bf16)v.z, (bf16)v.w};
    *(uint2*)(xdec_b + i) = *(const uint2*)o;
  } else if (id < 11152) {             // cast x_enc, 4 elems/thread
    int i = ((id - 7056) * 256 + threadIdx.x) * 4;
    float4 v = *(const float4*)(xenc + i);
    bf16 o[4] __attribute__((aligned(8))) =
        {(bf16)v.x, (bf16)v.y, (bf16)v.z, (bf16)v.w};
    *(uint2*)(xenc_b + i) = *(const uint2*)o;
  } else {
    int id2 = id - 11152;
    int kind = id2 >> 10, t = id2 & 1023;
    const float* in; bf16* out; int R, C, rt, ct;
    bool iperm = false, hsel = false; int hh = 0;
    if (kind == 0)      { in = Wq; out = BtQ; R = 2048; C = 512; rt = t >> 4; ct = t & 15; iperm = true; }
    else if (kind == 1) { in = Wk; out = BtK; R = 2048; C = 512; rt = t >> 4; ct = t & 15; iperm = true; }
    else if (kind == 2) { in = Wv; out = BtV; R = 2048; C = 512; rt = t >> 4; ct = t & 15; iperm = true; }
    else if (kind == 3) {              // WoTh[h][n][e] = Wo[4e+h][n]
      int zz = t >> 8, tt = t & 255;
      in = Wo; out = WoTh + (long)zz * 262144;
      R = 512; C = 512; rt = tt >> 4; ct = tt & 15; hsel = true; hh = zz;
    }
    else if (kind == 4) { in = W1; out = W1T; R = 512; C = 2048; rt = t >> 6; ct = t & 63; }
    else                { in = W2; out = W2T; R = 2048; C = 512; rt = t >> 4; ct = t & 15; }
    int c0 = ct * 32, r0 = rt * 32;
    int tx = threadIdx.x & 31, ty = threadIdx.x >> 5;
#pragma unroll
    for (int i = 0; i < 32; i += 8) {
      int r = r0 + ty + i;
      int rr = hsel ? (4 * r + hh) : r;
      tile[ty + i][tx] = (bf16)in[(long)rr * C + (c0 + tx)];
    }
    __syncthreads();
#pragma unroll
    for (int i = 0; i < 32; i += 8) {
      int cc = c0 + ty + i, rr = r0 + tx;
      if (iperm) {  // Bt row from W row h*512+din; cc = e, rr>>9 = h, rr&511 = din
        int e = cc, h = rr >> 9;
        int n = (e & 15) | (h << 4) | ((e >> 4) << 6);
        out[((long)n << 9) + (rr & 511)] = tile[tx][ty + i];
      } else {
        out[(long)cc * R + rr] = tile[tx][ty + i];
      }
    }
  }
}

// Fold Yt [4][512][4096] -> Yf2 [8][512][1088], 4 elems/thread (4352 blocks).
__global__ void __launch_bounds__(256) fold_y(const bf16* __restrict__ Yt,
                                              bf16* __restrict__ Yf2) {
  int idx = blockIdx.x * 256 + threadIdx.x;   // 1114112 = 8*512*272
  int k0 = (idx % 272) * 4;
  int rr = idx / 272;
  int j = rr & 511, z = rr >> 9;
  int b = z & 3, half = z >> 2;
  const bf16* yin = Yt + (long)b * 2097152 + (long)j * 4096;
  bf16 o[4] __attribute__((aligned(8)));
  if (half == 0) {
    bf16 f[4] __attribute__((aligned(8)));
    *(uint2*)f = *(const uint2*)(yin + k0);      // Y[k0..k0+3]
#pragma unroll
    for (int i = 0; i < 4; ++i) {
      int k = k0 + i;
      float v;
      if (k == 0)            v = (float)f[0];
      else if (k == 1024)    v = (float)f[i];
      else if (k < 1024)     v = (float)f[i] + (float)yin[2048 - k];
      else                   v = 0.0f;
      o[i] = (bf16)v;
    }
  } else {
    bf16 f[4] __attribute__((aligned(8)));
    *(uint2*)f = *(const uint2*)(yin + 2048 + k0); // Ys[k0..k0+3]
#pragma unroll
    for (int i = 0; i < 4; ++i) {
      int k = k0 + i;
      float v = 0.0f;
      if (k >= 1 && k <= 1023) v = (float)f[i] - (float)yin[4096 - k];
      o[i] = (bf16)v;
    }
  }
  *(uint2*)(Yf2 + (long)z * 557056 + (long)j * 1088 + k0) = *(const uint2*)o;
}

// ---------------- LN1 with DFT recombination (pairwise vectorized) ----------------
__global__ void __launch_bounds__(256) ln1_kernel(
    const float* __restrict__ xdec, const bf16* __restrict__ CSb,
    const float* __restrict__ g, const float* __restrict__ be,
    bf16* __restrict__ outb) {
  const int row = blockIdx.x, t = threadIdx.x;
  const int b = row >> 11, s = row & 2047;
  const int sp = (s <= 1024) ? s : 2048 - s;
  const float sgn = (s <= 1024) ? 1.0f : -1.0f;
  const bf16* Crow = CSb + ((long)b * 1152 + sp) * 512;
  const bf16* Srow = CSb + ((long)(b + 4) * 1152 + sp) * 512;
  const long base = (long)row * 512;
  float2 xp = *(const float2*)(xdec + base + 2 * t);
  bf16 cp[2] __attribute__((aligned(4)));
  bf16 spv[2] __attribute__((aligned(4)));
  *(uint*)cp = *(const uint*)(Crow + 2 * t);
  *(uint*)spv = *(const uint*)(Srow + 2 * t);
  float v0 = xp.x + (float)cp[0] + sgn * (float)spv[0];
  float v1 = xp.y + (float)cp[1] + sgn * (float)spv[1];
  float sm = v0 + v1, q = v0 * v0 + v1 * v1;
#pragma unroll
  for (int off = 32; off > 0; off >>= 1) {
    sm += __shfl_down(sm, off);
    q += __shfl_down(q, off);
  }
  __shared__ float red[8];
  const int wv = t >> 6, ln = t & 63;
  if (ln == 0) { red[wv] = sm; red[wv + 4] = q; }
  __syncthreads();
  float S = red[0] + red[1] + red[2] + red[3];
  float Q = red[4] + red[5] + red[6] + red[7];
  float mu = S * (1.0f / 512.0f);
  float var = Q * (1.0f / 512.0f) - mu * mu;
  float rstd = rsqrtf(var + 1e-5f);
  float2 gp = *(const float2*)(g + 2 * t);
  float2 bp = *(const float2*)(be + 2 * t);
  bf16 op[2] __attribute__((aligned(4)));
  op[0] = (bf16)(gp.x * (v0 - mu) * rstd + bp.x);
  op[1] = (bf16)(gp.y * (v1 - mu) * rstd + bp.y);
  *(uint*)(outb + base + 2 * t) = *(const uint*)op;
}

// ---------------- LayerNorm over bf16 A + two bf16 partials (split-K sum) --------------
template <int WRITE_BF16, int WRITE_F32>
__global__ void __launch_bounds__(256) ln_sum2(
    const bf16* __restrict__ A, const bf16* __restrict__ P0,
    const bf16* __restrict__ P1,
    const float* __restrict__ g, const float* __restrict__ be,
    bf16* __restrict__ outb, float* __restrict__ outf) {
  const int row = blockIdx.x, t = threadIdx.x;
  const long base = (long)row * 512;
  bf16 ap[2] __attribute__((aligned(4)));
  bf16 p0[2] __attribute__((aligned(4)));
  bf16 p1[2] __attribute__((aligned(4)));
  *(uint*)ap = *(const uint*)(A + base + 2 * t);
  *(uint*)p0 = *(const uint*)(P0 + base + 2 * t);
  *(uint*)p1 = *(const uint*)(P1 + base + 2 * t);
  float v0 = (float)ap[0] + (float)p0[0] + (float)p1[0];
  float v1 = (float)ap[1] + (float)p0[1] + (float)p1[1];
  float s = v0 + v1, q = v0 * v0 + v1 * v1;
#pragma unroll
  for (int off = 32; off > 0; off >>= 1) {
    s += __shfl_down(s, off);
    q += __shfl_down(q, off);
  }
  __shared__ float red[8];
  const int wv = t >> 6, ln = t & 63;
  if (ln == 0) { red[wv] = s; red[wv + 4] = q; }
  __syncthreads();
  float S = red[0] + red[1] + red[2] + red[3];
  float Q = red[4] + red[5] + red[6] + red[7];
  float mu = S * (1.0f / 512.0f);
  float var = Q * (1.0f / 512.0f) - mu * mu;
  float rstd = rsqrtf(var + 1e-5f);
  float2 gp = *(const float2*)(g + 2 * t);
  float2 bp = *(const float2*)(be + 2 * t);
  float o0 = gp.x * (v0 - mu) * rstd + bp.x;
  float o1 = gp.y * (v1 - mu) * rstd + bp.y;
  if (WRITE_BF16) {
    bf16 op[2] __attribute__((aligned(4)));
    op[0] = (bf16)o0; op[1] = (bf16)o1;
    *(uint*)(outb + base + 2 * t) = *(const uint*)op;
  }
  if (WRITE_F32) {
    float2 of; of.x = o0; of.y = o1;
    *(float2*)(outf + base + 2 * t) = of;
  }
}

// ---------------- GEMM body: C = A[M,K] * Bt[N,K]^T (single-buffer m97 K-loop) ---------
template <int BN, int ADDR_MODE, int HAS_BIAS, int DO_SELU, int F32OUT, int SWIZ,
          int AHEAD>
static __device__ __forceinline__ void gemm_bt_body(
    int id, bf16* lA, bf16* lB,
    const bf16* __restrict__ A, const bf16* __restrict__ Bt,
    const float* __restrict__ bias, void* __restrict__ Cout,
    int N, int K, long sAz, long sBz, long sBiasz, long sCz,
    int gx, int gy, int gin) {
  int x, y, z;
  {
    if (SWIZ == 0) {
      x = id % gx; int t2 = id / gx; y = t2 % gy; z = t2 / gy;
    } else {
      int xcd = id & 7, r = id >> 3;
      int inner = r % gin, G = xcd + 8 * (r / gin);
      if (SWIZ == 1)      { y = G; x = inner % gx; z = inner / gx; }
      else if (SWIZ == 2) { z = G; x = inner % gx; y = inner / gx; }
      else                { x = G; y = inner % gy; z = inner / gy; }
    }
  }
  A  += (AHEAD == 1) ? sAz * (z & 3) : (AHEAD == 2) ? sAz * (z >> 2) : sAz * z;
  Bt += sBz * z;
  const int m0 = y * 128, n0 = x * BN;
  const int t = threadIdx.x;
  const int lane = t & 63, wave = t >> 6;
  const int srow = t >> 3;
  const int pch  = t & 7;
  const int lch  = pch ^ (srow & 7);   // XOR bank swizzle (global-side)
  const bf16* Ag = A  + (long)(m0 + srow) * K + lch * 8;
  const bf16* Bg = Bt + (long)(n0 + srow) * K + lch * 8;
  bf16* lAp = lA + srow * 64 + pch * 8;
  bf16* lBp = lB + srow * 64 + pch * 8;
  constexpr int MI = (BN == 128) ? 4 : 2;
  const int wm = (BN == 128) ? (wave >> 1) * 64 : wave * 32;
  const int wn = (BN == 128) ? (wave & 1) * 64 : 0;
  const int fr = lane & 15, fq = lane >> 4;

  f32x4 acc[MI][4] = {};

  for (int k0 = 0; k0 < K; k0 += 64) {
    __syncthreads();
#pragma unroll
    for (int i = 0; i < 4; ++i)
      async16(Ag + k0 + (long)(32 * i) * K, lAp + 32 * i * 64);
#pragma unroll
    for (int i = 0; i < BN / 32; ++i)
      async16(Bg + k0 + (long)(32 * i) * K, lBp + 32 * i * 64);
    __syncthreads();
#pragma unroll
    for (int kk = 0; kk < 2; ++kk) {
      bf16x8 av[MI], bfrag[4];
#pragma unroll
      for (int mi = 0; mi < MI; ++mi) {
        int r = wm + mi * 16 + fr;
        int c = (kk * 4 + fq) ^ (r & 7);
        av[mi] = *(const bf16x8*)&lA[r * 64 + c * 8];
      }
#pragma unroll
      for (int ni = 0; ni < 4; ++ni) {
        int r = wn + ni * 16 + fr;
        int c = (kk * 4 + fq) ^ (r & 7);
        bfrag[ni] = *(const bf16x8*)&lB[r * 64 + c * 8];
      }
#pragma unroll
      for (int mi = 0; mi < MI; ++mi)
#pragma unroll
        for (int ni = 0; ni < 4; ++ni)
          acc[mi][ni] = __builtin_amdgcn_mfma_f32_16x16x32_bf16(
              av[mi], bfrag[ni], acc[mi][ni], 0, 0, 0);
    }
  }

  // epilogue: C/D layout col = lane&15, row = (lane>>4)*4 + reg
#pragma unroll
  for (int mi = 0; mi < MI; ++mi) {
#pragma unroll
    for (int ni = 0; ni < 4; ++ni) {
      const int col = n0 + wn + ni * 16 + fr;
      float bias_v = 0.0f;
      if (HAS_BIAS == 1) bias_v = bias[sBiasz * z + col];
      if (ADDR_MODE == 9) {                  // z=b*4+h -> Bt_b[row][(col&15)|(h<<4)|((col>>4)<<6)]
        const int b = z >> 2, h = z & 3;
        const int kidx = (col & 15) | (h << 4) | ((col >> 4) << 6);
#pragma unroll
        for (int r = 0; r < 4; ++r) {
          const int row = m0 + wm + mi * 16 + fq * 4 + r;
          ((bf16*)Cout)[((long)(b * 512 + row)) * 2048 + kidx] =
              (bf16)(acc[mi][ni][r] + bias_v);
        }
      } else {
#pragma unroll
        for (int r = 0; r < 4; ++r) {
          const int row = m0 + wm + mi * 16 + fq * 4 + r;
          float v = acc[mi][ni][r] + bias_v;
          if (DO_SELU) v = v > 0.0f ? 1.0507009873554805f * v
                                    : 1.7580993408473766f * (__expf(v) - 1.0f);
          long addr = sCz * z + (long)row * N + col;
          if (F32OUT) ((float*)Cout)[addr] = v;
          else        ((bf16*)Cout)[addr] = (bf16)v;
        }
      }
    }
  }
}

// standalone wrapper
template <int BN, int ADDR_MODE, int HAS_BIAS, int DO_SELU, int F32OUT, int SWIZ,
          int AHEAD = 0>
__global__ void __launch_bounds__(256, 2) gemm_bt(
    const bf16* __restrict__ A, const bf16* __restrict__ Bt,
    const float* __restrict__ bias, void* __restrict__ Cout,
    int N, int K, long sAz, long sBz, long sBiasz, long sCz,
    int gx, int gy, int gin) {
  __shared__ __align__(16) bf16 lA[128 * 64];
  __shared__ __align__(16) bf16 lB[BN * 64];
  gemm_bt_body<BN, ADDR_MODE, HAS_BIAS, DO_SELU, F32OUT, SWIZ, AHEAD>(
      blockIdx.x, lA, lB, A, Bt, bias, Cout, N, K, sAz, sBz, sBiasz, sCz, gx, gy, gin);
}

// ---------------- split-K dual-N GEMM: 128x128 output, K halved, bf16 partials ---------
// Shapes here: K=2048, N=512, A row-stride 2048. Two 64-wide N-tiles share the A tile:
// per k-step 8 global_load_lds -> 32 MFMA (2x the BN=64 density). 512 blocks, 32KiB LDS.
// Z4=1 (attn): z in [0,4) batches, y in [0,16). Z4=0 (W2): y in [0,64).
// Partial P[ks][row][col] bf16 (LN normalizes -> rounding scaled by row std; same
// precision class as round-13's bf16 full-value stores which passed); bias once (ks==0).
template <int Z4>
__global__ void __launch_bounds__(256, 2) gemm_sk2(
    const bf16* __restrict__ A, const bf16* __restrict__ Bt,
    const float* __restrict__ bias,
    bf16* __restrict__ P0, bf16* __restrict__ P1,
    long sAz, long sBz) {
  __shared__ __align__(16) bf16 lA[128 * 64];
  __shared__ __align__(16) bf16 lB[2][64 * 64];
  const int id = blockIdx.x;            // [0,512)
  const int xcd = id & 7, r = id >> 3;  // r in [0,64)
  const int xp = r & 3;
  int y, z, ks;
  if (Z4) { z = xcd >> 1; ks = xcd & 1; y = r >> 2; }
  else    { z = 0; ks = xcd & 1; y = (xcd >> 1) * 16 + (r >> 2); }
  const int K = 2048, KH = 1024;
  A  += (long)z * sAz + (long)ks * KH;
  Bt += (long)z * sBz + (long)ks * KH;
  const int m0 = y * 128, n0 = xp * 128;
  const int t = threadIdx.x;
  const int lane = t & 63, wave = t >> 6;
  const int srow = t >> 3, pch = t & 7, lch = pch ^ (srow & 7);
  const bf16* Ag  = A  + (long)(m0 + srow) * K + lch * 8;
  const bf16* B0g = Bt + (long)(n0 + srow) * K + lch * 8;
  const bf16* B1g = Bt + (long)(n0 + 64 + srow) * K + lch * 8;
  bf16* lAp  = lA + srow * 64 + pch * 8;
  bf16* lB0p = lB[0] + srow * 64 + pch * 8;
  bf16* lB1p = lB[1] + srow * 64 + pch * 8;
  const int wm = wave * 32;             // 4 waves x 32 rows
  const int fr = lane & 15, fq = lane >> 4;

  f32x4 acc[2][2][4] = {};              // [set][mi][ni]
  for (int k0 = 0; k0 < KH; k0 += 64) {
    __syncthreads();
#pragma unroll
    for (int i = 0; i < 4; ++i)
      async16(Ag + k0 + (long)(32 * i) * K, lAp + 32 * i * 64);
#pragma unroll
    for (int i = 0; i < 2; ++i) {
      async16(B0g + k0 + (long)(32 * i) * K, lB0p + 32 * i * 64);
      async16(B1g + k0 + (long)(32 * i) * K, lB1p + 32 * i * 64);
    }
    __syncthreads();
#pragma unroll
    for (int kk = 0; kk < 2; ++kk) {
      bf16x8 av[2];
#pragma unroll
      for (int mi = 0; mi < 2; ++mi) {
        int rr = wm + mi * 16 + fr;
        int c = (kk * 4 + fq) ^ (rr & 7);
        av[mi] = *(const bf16x8*)&lA[rr * 64 + c * 8];
      }
#pragma unroll
      for (int s = 0; s < 2; ++s) {
        bf16x8 bfrag[4];
#pragma unroll
        for (int ni = 0; ni < 4; ++ni) {
          int rr = ni * 16 + fr;
          int c = (kk * 4 + fq) ^ (rr & 7);
          bfrag[ni] = *(const bf16x8*)&lB[s][rr * 64 + c * 8];
        }
#pragma unroll
        for (int mi = 0; mi < 2; ++mi)
#pragma unroll
          for (int ni = 0; ni < 4; ++ni)
            acc[s][mi][ni] = __builtin_amdgcn_mfma_f32_16x16x32_bf16(
                av[mi], bfrag[ni], acc[s][mi][ni], 0, 0, 0);
      }
    }
  }

  bf16* P = ks ? P1 : P0;
#pragma unroll
  for (int s = 0; s < 2; ++s) {
#pragma unroll
    for (int mi = 0; mi < 2; ++mi) {
#pragma unroll
      for (int ni = 0; ni < 4; ++ni) {
        const int col = n0 + s * 64 + ni * 16 + fr;
        const float bias_v = (ks == 0) ? bias[col] : 0.0f;
#pragma unroll
        for (int r2 = 0; r2 < 4; ++r2) {
          const int row = m0 + wm + mi * 16 + fq * 4 + r2;
          const long addr = ((long)(Z4 ? z * 2048 + row : row)) * 512 + col;
          P[addr] = (bf16)(acc[s][mi][ni][r2] + bias_v);
        }
      }
    }
  }
}

// ---------------- Q projection GEMM body (id in [0,1024)) ------------------------------
// BtQ permuted row order -> h == ni: register-axis head-softmax, writes qs2 (kidx).
static __device__ __forceinline__ void qkv_body(
    int id, bf16* lA, bf16* lB,
    const bf16* __restrict__ Aq,
    const bf16* __restrict__ BQ,
    const float* __restrict__ bq,
    bf16* __restrict__ qs2) {
  const int sid = id & 1023;
  const int xcd = sid & 7, r = sid >> 3;
  const int x = r & 15, y = xcd + 8 * (r >> 4);
  const bf16 *A = Aq, *Bt = BQ; bf16* out = qs2; const float* bias = bq;
  const int K = 512;
  const int m0 = y * 128, n0 = x * 128;
  const int t = threadIdx.x;
  const int lane = t & 63, wave = t >> 6;
  const int srow = t >> 3, pch = t & 7, lch = pch ^ (srow & 7);
  const bf16* Ag = A  + (long)(m0 + srow) * K + lch * 8;
  const bf16* Bg = Bt + (long)(n0 + srow) * K + lch * 8;
  bf16* lAp = lA + srow * 64 + pch * 8;
  bf16* lBp = lB + srow * 64 + pch * 8;
  const int wm = (wave >> 1) * 64, wn = (wave & 1) * 64;
  const int fr = lane & 15, fq = lane >> 4;

  f32x4 acc[4][4] = {};
  for (int k0 = 0; k0 < K; k0 += 64) {
    __syncthreads();
#pragma unroll
    for (int i = 0; i < 4; ++i) {
      async16(Ag + k0 + (long)(32 * i) * K, lAp + 32 * i * 64);
      async16(Bg + k0 + (long)(32 * i) * K, lBp + 32 * i * 64);
    }
    __syncthreads();
#pragma unroll
    for (int kk = 0; kk < 2; ++kk) {
      bf16x8 av[4], bfrag[4];
#pragma unroll
      for (int mi = 0; mi < 4; ++mi) {
        int rr = wm + mi * 16 + fr;
        int c = (kk * 4 + fq) ^ (rr & 7);
        av[mi] = *(const bf16x8*)&lA[rr * 64 + c * 8];
      }
#pragma unroll
      for (int ni = 0; ni < 4; ++ni) {
        int rr = wn + ni * 16 + fr;
        int c = (kk * 4 + fq) ^ (rr & 7);
        bfrag[ni] = *(const bf16x8*)&lB[rr * 64 + c * 8];
      }
#pragma unroll
      for (int mi = 0; mi < 4; ++mi)
#pragma unroll
        for (int ni = 0; ni < 4; ++ni)
          acc[mi][ni] = __builtin_amdgcn_mfma_f32_16x16x32_bf16(
              av[mi], bfrag[ni], acc[mi][ni], 0, 0, 0);
    }
  }

  // h == ni; e = fr + 16*((n0+wn)>>6). Softmax across ni in registers.
  const int ebase = fr + 16 * ((n0 + wn) >> 6);
  const float b0 = bias[ebase], b1 = bias[512 + ebase],
              b2 = bias[1024 + ebase], b3 = bias[1536 + ebase];
#pragma unroll
  for (int mi = 0; mi < 4; ++mi) {
#pragma unroll
    for (int r = 0; r < 4; ++r) {
      const int row = m0 + wm + mi * 16 + fq * 4 + r;
      float v0 = acc[mi][0][r] + b0;
      float v1 = acc[mi][1][r] + b1;
      float v2 = acc[mi][2][r] + b2;
      float v3 = acc[mi][3][r] + b3;
      float m = fmaxf(fmaxf(v0, v1), fmaxf(v2, v3));
      float p0 = __expf(v0 - m), p1 = __expf(v1 - m),
            p2 = __expf(v2 - m), p3 = __expf(v3 - m);
      float rs = 1.0f / (p0 + p1 + p2 + p3);
      const long ob = (long)row * 2048 + n0 + wn + fr;
      out[ob]      = (bf16)(p0 * rs);
      out[ob + 16] = (bf16)(p1 * rs);
      out[ob + 32] = (bf16)(p2 * rs);
      out[ob + 48] = (bf16)(p3 * rs);
    }
  }
}

// ---------------- merged K+V projection body (id in [0,1024)) --------------------------
static __device__ __forceinline__ void kv2_body(
    int sid, bf16* smem,
    const bf16* __restrict__ Aenc, const bf16* __restrict__ BK,
    const bf16* __restrict__ BV,
    const float* __restrict__ bk, const float* __restrict__ bv,
    bf16* __restrict__ ksT, bf16* __restrict__ vsT) {
  const int xcd = sid & 7, r = sid >> 3;
  const int x = r & 15, y = xcd + 8 * (r >> 4);
  const int K = 512;
  const int m0 = y * 128, n0 = x * 128;
  const int t = threadIdx.x;
  const int lane = t & 63, wave = t >> 6;
  const int srow = t >> 3, pch = t & 7, lch = pch ^ (srow & 7);
  bf16* lA  = smem;           // [0,8192) elems
  bf16* lBK = smem + 8192;    // [8192,16384)
  bf16* lBV = smem + 16384;   // [16384,24576)
  const bf16* Ag  = Aenc + (long)(m0 + srow) * K + lch * 8;
  const bf16* BKg = BK   + (long)(n0 + srow) * K + lch * 8;
  const bf16* BVg = BV   + (long)(n0 + srow) * K + lch * 8;
  bf16* lAp  = lA  + srow * 64 + pch * 8;
  bf16* lBKp = lBK + srow * 64 + pch * 8;
  bf16* lBVp = lBV + srow * 64 + pch * 8;
  const int wm = (wave >> 1) * 64, wn = (wave & 1) * 64;
  const int fr = lane & 15, fq = lane >> 4;

  f32x4 accK[4][4] = {}, accV[4][4] = {};
  for (int k0 = 0; k0 < K; k0 += 64) {
    __syncthreads();
#pragma unroll
    for (int i = 0; i < 4; ++i) {
      async16(Ag  + k0 + (long)(32 * i) * K, lAp  + 32 * i * 64);
      async16(BKg + k0 + (long)(32 * i) * K, lBKp + 32 * i * 64);
      async16(BVg + k0 + (long)(32 * i) * K, lBVp + 32 * i * 64);
    }
    __syncthreads();
#pragma unroll
    for (int kk = 0; kk < 2; ++kk) {
      bf16x8 av[4], bkf[4], bvf[4];
#pragma unroll
      for (int mi = 0; mi < 4; ++mi) {
        int rr = wm + mi * 16 + fr;
        int c = (kk * 4 + fq) ^ (rr & 7);
        av[mi] = *(const bf16x8*)&lA[rr * 64 + c * 8];
      }
#pragma unroll
      for (int ni = 0; ni < 4; ++ni) {
        int rr = wn + ni * 16 + fr;
        int c = (kk * 4 + fq) ^ (rr & 7);
        bkf[ni] = *(const bf16x8*)&lBK[rr * 64 + c * 8];
        bvf[ni] = *(const bf16x8*)&lBV[rr * 64 + c * 8];
      }
#pragma unroll
      for (int mi = 0; mi < 4; ++mi)
#pragma unroll
        for (int ni = 0; ni < 4; ++ni) {
          accK[mi][ni] = __builtin_amdgcn_mfma_f32_16x16x32_bf16(
              av[mi], bkf[ni], accK[mi][ni], 0, 0, 0);
          accV[mi][ni] = __builtin_amdgcn_mfma_f32_16x16x32_bf16(
              av[mi], bvf[ni], accV[mi][ni], 0, 0, 0);
        }
    }
  }

  // h == ni; feature index e = fr + 16*((n0+wn)>>6).
  const int ebase = fr + 16 * ((n0 + wn) >> 6);
  const float kb0 = bk[ebase], kb1 = bk[512 + ebase],
              kb2 = bk[1024 + ebase], kb3 = bk[1536 + ebase];
  const float vb0 = bv[ebase], vb1 = bv[512 + ebase],
              vb2 = bv[1024 + ebase], vb3 = bv[1536 + ebase];
  bf16* lT = smem;                       // 32 KiB contiguous (lA+lBK)
  const int bb = m0 >> 11;
  const int s_tile = m0 & 2047;
  const int e_loc = fr + 16 * (wn >> 6); // [0,32)
  const int c = lane & 15, rg = lane >> 4;

  // ---- K (softmax) ----
  __syncthreads();                       // all LDS reads of lA/lBK/lBV done
#pragma unroll
  for (int mi = 0; mi < 4; ++mi) {
    const int s0 = wm + mi * 16 + fq * 4;
    bf16 tmp[4][4] __attribute__((aligned(8)));   // [h][r]
#pragma unroll
    for (int r2 = 0; r2 < 4; ++r2) {
      float v0 = accK[mi][0][r2] + kb0;
      float v1 = accK[mi][1][r2] + kb1;
      float v2 = accK[mi][2][r2] + kb2;
      float v3 = accK[mi][3][r2] + kb3;
      float m = fmaxf(fmaxf(v0, v1), fmaxf(v2, v3));
      float p0 = __expf(v0 - m), p1 = __expf(v1 - m),
            p2 = __expf(v2 - m), p3 = __expf(v3 - m);
      float rs = 1.0f / (p0 + p1 + p2 + p3);
      tmp[0][r2] = (bf16)(p0 * rs); tmp[1][r2] = (bf16)(p1 * rs);
      tmp[2][r2] = (bf16)(p2 * rs); tmp[3][r2] = (bf16)(p3 * rs);
    }
#pragma unroll
    for (int ni = 0; ni < 4; ++ni) {
      const int row = ni * 32 + e_loc;
      const int el = row * 128 + ((((s0 >> 3) ^ (row & 15)) << 3) | (s0 & 7));
      *(uint2*)&lT[el] = *(const uint2*)tmp[ni];
    }
  }
  __syncthreads();
#pragma unroll
  for (int i = 0; i < 8; ++i) {
    const int row = wave * 32 + rg + i * 4;
    const int el = row * 128 + ((c ^ (row & 15)) << 3);
    uint4 v = *(const uint4*)&lT[el];
    const int h = row >> 5, e = (row & 31) + 32 * x;
    *(uint4*)(ksT + ((long)((bb * 4 + h) * 512 + e)) * 2048 + s_tile + c * 8) = v;
  }

  // ---- V (no softmax) ----
  __syncthreads();                       // lT reads complete
#pragma unroll
  for (int mi = 0; mi < 4; ++mi) {
    const int s0 = wm + mi * 16 + fq * 4;
    bf16 tmp[4][4] __attribute__((aligned(8)));
#pragma unroll
    for (int r2 = 0; r2 < 4; ++r2) {
      tmp[0][r2] = (bf16)(accV[mi][0][r2] + vb0);
      tmp[1][r2] = (bf16)(accV[mi][1][r2] + vb1);
      tmp[2][r2] = (bf16)(accV[mi][2][r2] + vb2);
      tmp[3][r2] = (bf16)(accV[mi][3][r2] + vb3);
    }
#pragma unroll
    for (int ni = 0; ni < 4; ++ni) {
      const int row = ni * 32 + e_loc;
      const int el = row * 128 + ((((s0 >> 3) ^ (row & 15)) << 3) | (s0 & 7));
      *(uint2*)&lT[el] = *(const uint2*)tmp[ni];
    }
  }
  __syncthreads();
#pragma unroll
  for (int i = 0; i < 8; ++i) {
    const int row = wave * 32 + rg + i * 4;
    const int el = row * 128 + ((c ^ (row & 15)) << 3);
    uint4 v = *(const uint4*)&lT[el];
    const int h = row >> 5, e = (row & 31) + 32 * x;
    *(uint4*)(vsT + ((long)((bb * 4 + h) * 512 + e)) * 2048 + s_tile + c * 8) = v;
  }
}

// ---------------- fused launches ----------------
// [0,1024): merged K+V projection | [1024,1536): Yt DFT GEMM
__global__ void __launch_bounds__(256, 2) fused_kv_yt(
    const bf16* __restrict__ Aenc, const bf16* __restrict__ BK,
    const bf16* __restrict__ BV,
    const float* __restrict__ bk, const float* __restrict__ bv,
    bf16* __restrict__ ksT, bf16* __restrict__ vsT,
    const bf16* __restrict__ Ttrig, const bf16* __restrict__ xdec_b,
    bf16* __restrict__ Yt) {
  __shared__ __align__(16) bf16 smem[24576];   // 48 KiB
  int id = blockIdx.x;
  if (id < 1024)
    kv2_body(id, smem, Aenc, BK, BV, bk, bv, ksT, vsT);
  else
    gemm_bt_body<128, 0, 0, 0, 0, 3, 0>(id - 1024, smem, smem + 8192,
        Ttrig, xdec_b, nullptr, Yt, 2048, 512, 0L, 1048576L, 0L, 2097152L, 16, 8, 32);
}

// [0,512): gc GEMM | [512,1088): CS GEMM
__global__ void __launch_bounds__(256, 2) fused_gc_cs(
    const bf16* __restrict__ ksT, const bf16* __restrict__ vsT,
    bf16* __restrict__ gc,
    const bf16* __restrict__ Atrig2, const bf16* __restrict__ Yf2,
    bf16* __restrict__ CSb) {
  __shared__ __align__(16) bf16 smem[12288];   // 24 KiB
  int id = blockIdx.x;
  if (id < 512)
    gemm_bt_body<64, 0, 0, 0, 0, 2, 0>(id, smem, smem + 8192,
        ksT, vsT, nullptr, gc, 512, 2048, 1048576L, 1048576L, 0L, 262144L, 8, 4, 32);
  else
    gemm_bt_body<64, 0, 0, 0, 0, 2, 2>(id - 512, smem, smem + 8192,
        Atrig2, Yf2, nullptr, CSb, 512, 1088, 1253376L, 557056L, 0L, 589824L, 8, 9, 72);
}

// [0,1024): Q projection + head-softmax | [1024,1536): gwT GEMM (kidx layout)
__global__ void __launch_bounds__(256, 2) fused_q_gw(
    const bf16* __restrict__ Aq, const bf16* __restrict__ BQ,
    const float* __restrict__ bq, bf16* __restrict__ qs2,
    const bf16* __restrict__ WoTh, const bf16* __restrict__ gc,
    bf16* __restrict__ gwT) {
  __shared__ __align__(16) bf16 smem[16384];   // 32 KiB
  int id = blockIdx.x;
  if (id < 1024)
    qkv_body(id, smem, smem + 8192, Aq, BQ, bq, qs2);
  else
    gemm_bt_body<64, 9, 0, 0, 0, 2, 1>(id - 1024, smem, smem + 8192,
        WoTh, gc, nullptr, gwT, 512, 512, 262144L, 262144L, 0L, 0L, 8, 4, 32);
}

// ---------------- launcher ----------------
extern "C" void kernel_launch(void* const* d_in, const int* in_sizes, int n_in,
                              void* d_out, int out_size, void* d_ws, size_t ws_size,
                              hipStream_t stream) {
  (void)in_sizes; (void)n_in; (void)out_size; (void)ws_size;
  const float* x_enc = (const float*)d_in[0];
  const float* x_dec = (const float*)d_in[1];
  const float* Wq = (const float*)d_in[2];
  const float* bq = (const float*)d_in[3];
  const float* Wk = (const float*)d_in[4];
  const float* bk = (const float*)d_in[5];
  const float* Wv = (const float*)d_in[6];
  const float* bv = (const float*)d_in[7];
  const float* Wo = (const float*)d_in[8];
  const float* bo = (const float*)d_in[9];
  const float* g1 = (const float*)d_in[10];
  const float* be1 = (const float*)d_in[11];
  const float* g2 = (const float*)d_in[12];
  const float* be2 = (const float*)d_in[13];
  const float* W1 = (const float*)d_in[14];
  const float* b1 = (const float*)d_in[15];
  const float* W2 = (const float*)d_in[16];
  const float* b2 = (const float*)d_in[17];
  const float* g3 = (const float*)d_in[18];
  const float* be3 = (const float*)d_in[19];

  char* ws = (char*)d_ws;
  const size_t MB = 1u << 20;
  // time-disjoint aliasing, peak 255 MiB. Launch order:
  // L1 prep | L2 kv+yt | L3 fold | L4 gc+cs | L5 ln1 | L6 q+gw | L7 attn(sk2)
  // L8 ln2(sum2) | L9 w1 | L10 w2(sk2) | L11 ln3(sum2)
  bf16*  BtQ    = (bf16*) (ws + 0);        // [0,2)   W:L1 R:L6
  bf16*  midb   = (bf16*) (ws + 0);        // [0,32)  W:L9 R:L10
  bf16*  ksT    = (bf16*) (ws + 32 * MB);  // [32,64) W:L2 R:L4
  bf16*  aP0    = (bf16*) (ws + 32 * MB);  // [32,40) W:L7 R:L8 (ksT dead after L4)
  bf16*  aP1    = (bf16*) (ws + 40 * MB);  // [40,48) W:L7 R:L8
  bf16*  vsT    = (bf16*) (ws + 64 * MB);  // [64,96) W:L2 R:L4
  bf16*  Atrig2 = (bf16*) (ws + 96 * MB);  // [96,101) W:L1 R:L4
  bf16*  Ttrig  = (bf16*) (ws + 101 * MB); // [101,102) W:L1 R:L2
  bf16*  CSb    = (bf16*) (ws + 102 * MB); // [102,112) W:L4 R:L5
  bf16*  qs2    = (bf16*) (ws + 96 * MB);  // [96,128) W:L6 R:L7
  bf16*  xenc_b = (bf16*) (ws + 128 * MB); // [128,136) W:L1 R:L2
  bf16*  wP0    = (bf16*) (ws + 128 * MB); // [128,136) W:L10 R:L11 (dead after L2)
  bf16*  wP1    = (bf16*) (ws + 144 * MB); // [144,152) W:L10 R:L11
  bf16*  BtK    = (bf16*) (ws + 136 * MB); // [136,138) W:L1 R:L2
  bf16*  BtV    = (bf16*) (ws + 138 * MB); // [138,140) W:L1 R:L2
  bf16*  xd_b   = (bf16*) (ws + 192 * MB); // [192,200) W:L5 R:L6,L8
  bf16*  x2_b   = (bf16*) (ws + 200 * MB); // [200,208) W:L8 R:L9,L11
  bf16*  gwT    = (bf16*) (ws + 208 * MB); // [208,216) W:L6 R:L7
  bf16*  Yt     = (bf16*) (ws + 216 * MB); // [216,232) W:L2 R:L3
  bf16*  gc     = (bf16*) (ws + 216 * MB); // [216,224) W:L4 R:L6 (Yt dead after L3)
  bf16*  Yf2    = (bf16*) (ws + 232 * MB); // [232,241) W:L3 R:L4
  bf16*  WoTh   = (bf16*) (ws + 241 * MB); // [241,243) W:L1 R:L6
  bf16*  W1T    = (bf16*) (ws + 243 * MB); // W:L1 R:L9
  bf16*  W2T    = (bf16*) (ws + 245 * MB); // W:L1 R:L10
  bf16*  xdec_b = (bf16*) (ws + 247 * MB); // [247,255) W:L1 R:L2

  // --- L1: prep (trig + casts x4-vectorized) ---
  prep_all<<<17296, 256, 0, stream>>>(x_dec, x_enc, Ttrig, Atrig2, xdec_b, xenc_b,
                                      Wq, Wk, Wv, Wo, W1, W2,
                                      BtQ, BtK, BtV, WoTh, W1T, W2T);

  // --- L2: merged K+V projection (A-tile shared)  ∥  Yt DFT GEMM ---
  fused_kv_yt<<<1536, 256, 0, stream>>>(xenc_b, BtK, BtV, bk, bv, ksT, vsT,
                                        Ttrig, xdec_b, Yt);

  // --- L3: fold (4 elems/thread) ---
  fold_y<<<4352, 256, 0, stream>>>(Yt, Yf2);

  // --- L4: gc GEMM  ∥  CS GEMM ---
  fused_gc_cs<<<1088, 256, 0, stream>>>(ksT, vsT, gc, Atrig2, Yf2, CSb);

  // --- L5: LN1 ---
  ln1_kernel<<<8192, 256, 0, stream>>>(x_dec, CSb, g1, be1, xd_b);

  // --- L6: Q projection+softmax  ∥  gwT ---
  fused_q_gw<<<1536, 256, 0, stream>>>(xd_b, BtQ, bq, qs2, WoTh, gc, gwT);

  // --- L7: attn split-K dual-N: bf16 partials P0/P1, bias once ---
  gemm_sk2<1><<<512, 256, 0, stream>>>(qs2, gwT, bo, aP0, aP1,
                                       4194304L, 1048576L);
  // --- L8: LN2 over xd + P0 + P1 ---
  ln_sum2<1, 0><<<8192, 256, 0, stream>>>(xd_b, aP0, aP1, g2, be2, x2_b, nullptr);

  // --- L9: FFN W1 + SELU ---
  gemm_bt<128, 0, 1, 1, 0, 1><<<1024, 256, 0, stream>>>(
      x2_b, W1T, b1, midb, 2048, 512, 0L, 0L, 0L, 0L, 16, 64, 16);
  // --- L10: FFN W2 split-K dual-N: bf16 partials ---
  gemm_sk2<0><<<512, 256, 0, stream>>>(midb, W2T, b2, wP0, wP1, 0L, 0L);
  // --- L11: LN3 over x2 + P0 + P1 -> output (f32) ---
  ln_sum2<0, 1><<<8192, 256, 0, stream>>>(x2_b, wP0, wP1, g3, be3, nullptr,
                                          (float*)d_out);
}